// Round 9
// baseline (2430.794 us; speedup 1.0000x reference)
//
#include <hip/hip_runtime.h>

// ---------------------------------------------------------------------------
// SharedOnlyMLP r9: B (weights) via global->VGPR direct, A-only LDS.
//   Both GEMMs were LDS-BW-bound (r8 analysis). B-frags consumed by 2 waves,
//   reused 8x from regs -> load direct, software-pipelined 1 step ahead with
//   named cur/next register sets. LDS traffic -40%.
//   i8gu: r7-proven 16x16x64 i8 inner loop, 4-ring of 16KB A-buffers.
//   down: r7-proven 16x16x32 bf16, 2-buffer of 32KB A.
//   vmcnt(6) counted wait per step/tile; in-order vmem retirement makes the
//   B-wait also guarantee the older A-stage. pack/quant prepass = r7.
// ---------------------------------------------------------------------------

typedef __attribute__((ext_vector_type(8))) __bf16 bf16x8;
typedef __attribute__((ext_vector_type(4))) float f32x4;
typedef __attribute__((ext_vector_type(8))) unsigned short ushort8;
typedef __attribute__((ext_vector_type(4))) int i32x4;

#define D_MODEL 4096
#define D_FF    11008
#define NTOK    8192

static __device__ __forceinline__ unsigned short f32_to_bf16(float f) {
    union { float f; unsigned u; } v; v.f = f;
    unsigned r = v.u + 0x7fffu + ((v.u >> 16) & 1u);
    return (unsigned short)(r >> 16);
}
static __device__ __forceinline__ void gload_lds16(const void* g, void* l) {
    __builtin_amdgcn_global_load_lds(
        (const __attribute__((address_space(1))) void*)g,
        (__attribute__((address_space(3))) void*)l, 16, 0, 0);
}

// ---- pack gate+up int32 -> interleaved int8 (16-row groups, r7) ----
__global__ __launch_bounds__(256)
void pack_gu_kernel(const int* __restrict__ gw, const int* __restrict__ uw,
                    signed char* __restrict__ out)
{
    long long i = ((long long)blockIdx.x * 256 + threadIdx.x) * 8;
    const int r = (int)(i >> 12);
    const int k = (int)(i & 4095);
    const int src_row = ((r >> 5) << 4) + (r & 15);
    const int* src = ((r >> 4) & 1) ? uw : gw;
    const int* p = src + (size_t)src_row * D_MODEL + k;
    int4 w0 = *(const int4*)(p);
    int4 w1 = *(const int4*)(p + 4);
    union { signed char c[8]; unsigned long long u; } rr;
    rr.c[0] = (signed char)w0.x; rr.c[1] = (signed char)w0.y;
    rr.c[2] = (signed char)w0.z; rr.c[3] = (signed char)w0.w;
    rr.c[4] = (signed char)w1.x; rr.c[5] = (signed char)w1.y;
    rr.c[6] = (signed char)w1.z; rr.c[7] = (signed char)w1.w;
    *(unsigned long long*)(out + i) = rr.u;
}

// ---- weight dequant (down-proj): int32 * s[row] -> bf16 ----
__global__ __launch_bounds__(256)
void dequant_w_kernel(const int* __restrict__ w, const float* __restrict__ s,
                      unsigned short* __restrict__ out, int cols, long long total)
{
    long long i = ((long long)blockIdx.x * 256 + threadIdx.x) * 8;
    if (i >= total) return;
    float sc = s[(int)(i / cols)];
    int4 w0 = *(const int4*)(w + i);
    int4 w1 = *(const int4*)(w + i + 4);
    ushort8 r;
    r[0] = f32_to_bf16((float)w0.x * sc);
    r[1] = f32_to_bf16((float)w0.y * sc);
    r[2] = f32_to_bf16((float)w0.z * sc);
    r[3] = f32_to_bf16((float)w0.w * sc);
    r[4] = f32_to_bf16((float)w1.x * sc);
    r[5] = f32_to_bf16((float)w1.y * sc);
    r[6] = f32_to_bf16((float)w1.z * sc);
    r[7] = f32_to_bf16((float)w1.w * sc);
    *(ushort8*)(out + i) = r;
}

// ---- x: f32 -> per-row int8 + scale ----
__global__ __launch_bounds__(256)
void quant_x_kernel(const float* __restrict__ x, signed char* __restrict__ xq,
                    float* __restrict__ xs)
{
    __shared__ float red[4];
    const int row = blockIdx.x;
    const int t   = threadIdx.x;
    const float* xr = x + (size_t)row * D_MODEL;
    float4 v0 = *(const float4*)(xr + t * 16);
    float4 v1 = *(const float4*)(xr + t * 16 + 4);
    float4 v2 = *(const float4*)(xr + t * 16 + 8);
    float4 v3 = *(const float4*)(xr + t * 16 + 12);
    float m = fabsf(v0.x);
    m = fmaxf(m, fabsf(v0.y)); m = fmaxf(m, fabsf(v0.z)); m = fmaxf(m, fabsf(v0.w));
    m = fmaxf(m, fabsf(v1.x)); m = fmaxf(m, fabsf(v1.y)); m = fmaxf(m, fabsf(v1.z)); m = fmaxf(m, fabsf(v1.w));
    m = fmaxf(m, fabsf(v2.x)); m = fmaxf(m, fabsf(v2.y)); m = fmaxf(m, fabsf(v2.z)); m = fmaxf(m, fabsf(v2.w));
    m = fmaxf(m, fabsf(v3.x)); m = fmaxf(m, fabsf(v3.y)); m = fmaxf(m, fabsf(v3.z)); m = fmaxf(m, fabsf(v3.w));
    #pragma unroll
    for (int o = 32; o > 0; o >>= 1) m = fmaxf(m, __shfl_xor(m, o));
    if ((t & 63) == 0) red[t >> 6] = m;
    __syncthreads();
    m = fmaxf(fmaxf(red[0], red[1]), fmaxf(red[2], red[3]));
    m = fmaxf(m, 1e-20f);
    const float inv = 127.0f / m;
    if (t == 0) xs[row] = m / 127.0f;
    union { signed char c[16]; int4 i; } r;
    #pragma unroll
    for (int j = 0; j < 4; ++j) {
        float4 v = (j == 0) ? v0 : (j == 1) ? v1 : (j == 2) ? v2 : v3;
        r.c[j*4+0] = (signed char)(int)rintf(fminf(fmaxf(v.x*inv,-127.f),127.f));
        r.c[j*4+1] = (signed char)(int)rintf(fminf(fmaxf(v.y*inv,-127.f),127.f));
        r.c[j*4+2] = (signed char)(int)rintf(fminf(fmaxf(v.z*inv,-127.f),127.f));
        r.c[j*4+3] = (signed char)(int)rintf(fminf(fmaxf(v.w*inv,-127.f),127.f));
    }
    *(int4*)(xq + (size_t)row * D_MODEL + t * 16) = r.i;
}

// ---------------------------------------------------------------------------
// Fused gate+up i8 GEMM, B direct-to-reg. A-only LDS: 4-ring x 16KB.
// Per step (BK=64): ph1 {4 ds_read A + 2 gload_lds A(s+2) + 4 glb B(s+1) +
// vmcnt(6) + 16 MFMA}, ph2 {4 ds_read A + 16 MFMA}.
// ---------------------------------------------------------------------------
__global__ __launch_bounds__(512, 2)
void gemm_i8gu(const signed char* __restrict__ A,
               const signed char* __restrict__ B,   // interleaved [2*D_FF][K]
               unsigned short* __restrict__ H,
               const float* __restrict__ xs,
               const float* __restrict__ gs,
               const float* __restrict__ us,
               int M, int NH, int K)
{
    extern __shared__ char smem[];
    const int tid = threadIdx.x;
    const int l   = tid & 63;
    const int w   = tid >> 6;
    const int wm  = w >> 2;
    const int wn  = w & 3;

    const int nbx  = gridDim.x;
    const int nwg  = nbx * gridDim.y;
    const int orig = blockIdx.y * nbx + blockIdx.x;
    const int cpx  = nwg >> 3;
    const int swz  = (orig & 7) * cpx + (orig >> 3);
    const int bn = swz % nbx, bm = swz / nbx;
    const int m0 = bm * 256, n0 = bn * 256;

    // A staging (A only)
    const int st_r = tid >> 2;
    const int st_c = ((tid & 3) ^ ((st_r >> 1) & 3)) << 4;
    const signed char* gA = A + (size_t)(m0 + st_r) * K + st_c;
    const size_t ld128 = (size_t)128 * K;

    // A ds_read offsets (swizzled) — r7-proven pattern
    const int s4v = l >> 4;
    const int rA = wm * 128 + (l & 15);
    const int offA = rA * 64 + ((s4v << 4) ^ (((rA >> 1) & 3) << 4));

    // B direct addressing: frag ni at step s = gB0 + ni*16*K + s*64
    const signed char* gB0 = B + (size_t)(n0 + wn * 64 + (l & 15)) * K
                               + ((l >> 4) << 4);
    const size_t bK16 = (size_t)16 * K;

    i32x4 acc[8][4] = {};
    i32x4 af[4];
    i32x4 bqa[4], bqb[4];

#define SBAR()  __builtin_amdgcn_sched_barrier(0)
#define BAR()   __builtin_amdgcn_s_barrier()
#define VM6()   asm volatile("s_waitcnt vmcnt(6)" ::: "memory")

#define ST_A(SS, NXT) do { \
    const signed char* p_ = gA + ((size_t)(SS) << 6); \
    gload_lds16(p_,         smem + (NXT) + (w << 10)); \
    gload_lds16(p_ + ld128, smem + (NXT) + 8192 + (w << 10)); } while (0)

#define LD_B(BQ, SB) do { \
    const signed char* q_ = gB0 + ((size_t)(SB) << 6); \
    BQ[0] = *(const i32x4*)(q_); \
    BQ[1] = *(const i32x4*)(q_ + bK16); \
    BQ[2] = *(const i32x4*)(q_ + 2 * bK16); \
    BQ[3] = *(const i32x4*)(q_ + 3 * bK16); } while (0)

#define MFMA16(MB, BQ) do { \
    _Pragma("unroll") \
    for (int mi_ = 0; mi_ < 4; ++mi_) { \
        _Pragma("unroll") \
        for (int ni_ = 0; ni_ < 4; ++ni_) { \
            acc[(MB) + mi_][ni_] = __builtin_amdgcn_mfma_i32_16x16x64_i8( \
                af[mi_], BQ[ni_], acc[(MB) + mi_][ni_], 0, 0, 0); \
        } } } while (0)

// step: read A from CUR + B from BC regs; stage A(SS)->NXT; load B(SB)->BN
#define STEP(CUR, NXT, SS, SB, BC, BN) do { \
    af[0] = *(const i32x4*)(smem + (CUR) + offA); \
    af[1] = *(const i32x4*)(smem + (CUR) + offA + 1024); \
    af[2] = *(const i32x4*)(smem + (CUR) + offA + 2048); \
    af[3] = *(const i32x4*)(smem + (CUR) + offA + 3072); \
    ST_A(SS, NXT); \
    LD_B(BN, SB); \
    SBAR(); BAR(); VM6(); SBAR(); \
    __builtin_amdgcn_s_setprio(1); MFMA16(0, BC); __builtin_amdgcn_s_setprio(0); \
    SBAR(); BAR(); \
    af[0] = *(const i32x4*)(smem + (CUR) + offA + 4096); \
    af[1] = *(const i32x4*)(smem + (CUR) + offA + 5120); \
    af[2] = *(const i32x4*)(smem + (CUR) + offA + 6144); \
    af[3] = *(const i32x4*)(smem + (CUR) + offA + 7168); \
    SBAR(); BAR(); \
    __builtin_amdgcn_s_setprio(1); MFMA16(4, BC); __builtin_amdgcn_s_setprio(0); \
    SBAR(); BAR(); \
} while (0)

    // prologue: stage A(0),A(1); load B(0); wait stages (oldest 4)
    ST_A(0, 0);
    ST_A(1, 16384);
    LD_B(bqa, 0);
    asm volatile("s_waitcnt vmcnt(4)" ::: "memory");
    SBAR(); BAR();

    const int T = K >> 6;            // 64; T%4==0
    #pragma unroll 1
    for (int s = 0; s < T; s += 4) {
        int b1 = s + 1;
        int s2 = s + 2; if (s2 >= T) s2 -= T;
        int s3 = s + 3; if (s3 >= T) s3 -= T;
        int s4 = s + 4; if (s4 >= T) s4 -= T;
        int s5 = s + 5; if (s5 >= T) s5 -= T;
        STEP(0,     32768, s2, b1, bqa, bqb);
        STEP(16384, 49152, s3, s2, bqb, bqa);
        STEP(32768, 0,     s4, s3, bqa, bqb);
        STEP(49152, 16384, s5, s4, bqb, bqa);
    }
    asm volatile("s_waitcnt vmcnt(0)" ::: "memory");

    // epilogue: ni even = gate, ni odd = up (16-row interleave, r7-proven)
    const int er = (l >> 4) * 4;
    const int ec = l & 15;
    const int hbase = (n0 >> 1) + wn * 32;
    #pragma unroll
    for (int mi = 0; mi < 8; ++mi) {
        const int rowb = m0 + wm * 128 + mi * 16 + er;
        const float4 xsv = *(const float4*)(xs + rowb);
        #pragma unroll
        for (int p = 0; p < 2; ++p) {
            const int c = hbase + p * 16 + ec;
            const float sg = gs[c];
            const float su = us[c];
            #pragma unroll
            for (int q = 0; q < 4; ++q) {
                const float xsc = (q == 0) ? xsv.x : (q == 1) ? xsv.y
                                 : (q == 2) ? xsv.z : xsv.w;
                float g = (float)acc[mi][2*p][q]     * sg * xsc;
                float u = (float)acc[mi][2*p + 1][q] * su * xsc;
                float sig = 1.0f / (1.0f + __expf(-g));
                H[(size_t)(rowb + q) * NH + c] = f32_to_bf16(g * sig * u);
            }
        }
    }
#undef STEP
#undef MFMA16
#undef LD_B
#undef ST_A
#undef VM6
#undef BAR
#undef SBAR
}

// ---------------------------------------------------------------------------
// Down-proj bf16 GEMM, B direct-to-reg. A-only LDS: 2 buffers x 32KB
// (half0 at +0, half1 at +16384 within a buffer). Tile (BK=64) = 4 phases;
// B(t+1) loaded 4 frags in ph1 (h0) + 4 in ph2 (h1); vmcnt(6) at ph1.
// ---------------------------------------------------------------------------
__global__ __launch_bounds__(512, 2)
void gemm256_down(const unsigned short* __restrict__ A,
                  const unsigned short* __restrict__ B,
                  float* __restrict__ C,
                  int M, int N, int K)
{
    extern __shared__ char smem[];
    const int tid = threadIdx.x;
    const int l   = tid & 63;
    const int w   = tid >> 6;
    const int wm  = w >> 2;
    const int wn  = w & 3;

    const int nbx  = gridDim.x;
    const int nwg  = nbx * gridDim.y;
    const int orig = blockIdx.y * nbx + blockIdx.x;
    const int cpx  = nwg >> 3;
    const int swz  = (orig & 7) * cpx + (orig >> 3);
    const int bn = swz % nbx, bm = swz / nbx;
    const int m0 = bm * 256, n0 = bn * 256;

    // A staging (bf16, r7 pattern)
    const int st_r = w * 16 + (l >> 2);
    const int st_c = (((l & 3) ^ ((l >> 3) & 3)) << 3);
    const unsigned short* gA = A + (size_t)(m0 + st_r) * K + st_c;
    const size_t ld128 = (size_t)128 * K;

    const int s4v = l >> 4;
    const int rA = wm * 128 + (l & 15);
    const int offA = rA * 64 + ((s4v << 4) ^ (((rA >> 1) & 3) << 4));

    // B direct: frag (ni, tile t, half h) = gB0 + ni*16*K + t*64 + h*32 (elems)
    const unsigned short* gB0 = B + (size_t)(n0 + wn * 64 + (l & 15)) * K
                                  + ((l >> 4) << 3);
    const size_t bK16 = (size_t)16 * K;

    f32x4 acc[8][4] = {};
    bf16x8 af[4];
    bf16x8 bca[8], bcb[8];

#define SBAR()  __builtin_amdgcn_sched_barrier(0)
#define BAR()   __builtin_amdgcn_s_barrier()
#define VM6()   asm volatile("s_waitcnt vmcnt(6)" ::: "memory")

#define ST_A2(SRC, LOFF) do { \
    gload_lds16((SRC), smem + (LOFF) + (w << 10)); \
    gload_lds16((SRC) + ld128, smem + (LOFF) + 8192 + (w << 10)); } while (0)

#define LD_B4(BQ, I0, TB, HF) do { \
    const unsigned short* q_ = gB0 + ((size_t)(TB) << 6) + (HF) * 32; \
    BQ[(I0) + 0] = *(const bf16x8*)(q_); \
    BQ[(I0) + 1] = *(const bf16x8*)(q_ + bK16); \
    BQ[(I0) + 2] = *(const bf16x8*)(q_ + 2 * bK16); \
    BQ[(I0) + 3] = *(const bf16x8*)(q_ + 3 * bK16); } while (0)

#define MFMA16B(MB, BQ, B0) do { \
    _Pragma("unroll") \
    for (int mi_ = 0; mi_ < 4; ++mi_) { \
        _Pragma("unroll") \
        for (int ni_ = 0; ni_ < 4; ++ni_) { \
            acc[(MB) + mi_][ni_] = __builtin_amdgcn_mfma_f32_16x16x32_bf16( \
                af[mi_], BQ[(B0) + ni_], acc[(MB) + mi_][ni_], 0, 0, 0); \
        } } } while (0)

// tile: read A from CB + B from BC; stage A(TN)->PB; load B(TN)->BN
#define TILE(CB, PB, TN, BC, BN) do { \
    const unsigned short* sA = gA + ((size_t)(TN) << 6); \
    /* ph1: h0 mi0-3 */ \
    af[0] = *(const bf16x8*)(smem + (CB) + offA); \
    af[1] = *(const bf16x8*)(smem + (CB) + offA + 1024); \
    af[2] = *(const bf16x8*)(smem + (CB) + offA + 2048); \
    af[3] = *(const bf16x8*)(smem + (CB) + offA + 3072); \
    ST_A2(sA, PB); \
    LD_B4(BN, 0, TN, 0); \
    SBAR(); BAR(); VM6(); SBAR(); \
    __builtin_amdgcn_s_setprio(1); MFMA16B(0, BC, 0); __builtin_amdgcn_s_setprio(0); \
    SBAR(); BAR(); \
    /* ph2: h0 mi4-7 */ \
    af[0] = *(const bf16x8*)(smem + (CB) + offA + 4096); \
    af[1] = *(const bf16x8*)(smem + (CB) + offA + 5120); \
    af[2] = *(const bf16x8*)(smem + (CB) + offA + 6144); \
    af[3] = *(const bf16x8*)(smem + (CB) + offA + 7168); \
    ST_A2(sA + 32, PB + 16384); \
    LD_B4(BN, 4, TN, 1); \
    SBAR(); BAR(); \
    __builtin_amdgcn_s_setprio(1); MFMA16B(4, BC, 0); __builtin_amdgcn_s_setprio(0); \
    SBAR(); BAR(); \
    /* ph3: h1 mi0-3 */ \
    af[0] = *(const bf16x8*)(smem + (CB) + 16384 + offA); \
    af[1] = *(const bf16x8*)(smem + (CB) + 16384 + offA + 1024); \
    af[2] = *(const bf16x8*)(smem + (CB) + 16384 + offA + 2048); \
    af[3] = *(const bf16x8*)(smem + (CB) + 16384 + offA + 3072); \
    SBAR(); BAR(); \
    __builtin_amdgcn_s_setprio(1); MFMA16B(0, BC, 4); __builtin_amdgcn_s_setprio(0); \
    SBAR(); BAR(); \
    /* ph4: h1 mi4-7 */ \
    af[0] = *(const bf16x8*)(smem + (CB) + 16384 + offA + 4096); \
    af[1] = *(const bf16x8*)(smem + (CB) + 16384 + offA + 5120); \
    af[2] = *(const bf16x8*)(smem + (CB) + 16384 + offA + 6144); \
    af[3] = *(const bf16x8*)(smem + (CB) + 16384 + offA + 7168); \
    SBAR(); BAR(); \
    __builtin_amdgcn_s_setprio(1); MFMA16B(4, BC, 4); __builtin_amdgcn_s_setprio(0); \
    SBAR(); BAR(); \
} while (0)

    // prologue: stage tile 0 (4 ops) + load B(0) (8 ops)
    ST_A2(gA, 0);
    ST_A2(gA + 32, 16384);
    LD_B4(bca, 0, 0, 0);
    LD_B4(bca, 4, 0, 1);
    SBAR(); BAR();   // tile0 ph1 VM6 drains prologue stages+B

    const int T = K >> 6;            // 172 (even)
    #pragma unroll 1
    for (int t = 0; t < T; t += 2) {
        const int t1 = t + 1;
        const int t2 = (t + 2 == T) ? 0 : (t + 2);   // dummy restage at end
        TILE(0,     32768, t1, bca, bcb);
        TILE(32768, 0,     t2, bcb, bca);
    }
    asm volatile("s_waitcnt vmcnt(0)" ::: "memory");

    const int er = (l >> 4) * 4;
    const int ec = l & 15;
    #pragma unroll
    for (int mi = 0; mi < 8; ++mi) {
        #pragma unroll
        for (int ni = 0; ni < 4; ++ni) {
            #pragma unroll
            for (int q = 0; q < 4; ++q) {
                int row = m0 + wm * 128 + mi * 16 + er + q;
                int col = n0 + wn * 64  + ni * 16 + ec;
                C[(size_t)row * N + col] = acc[mi][ni][q];
            }
        }
    }
#undef TILE
#undef MFMA16B
#undef LD_B4
#undef ST_A2
#undef VM6
#undef BAR
#undef SBAR
}

extern "C" void kernel_launch(void* const* d_in, const int* in_sizes, int n_in,
                              void* d_out, int out_size, void* d_ws, size_t ws_size,
                              hipStream_t stream)
{
    const float* x  = (const float*)d_in[0];
    const int*   gw = (const int*)  d_in[1];
    const float* gs = (const float*)d_in[2];
    const int*   uw = (const int*)  d_in[3];
    const float* us = (const float*)d_in[4];
    const int*   dw = (const int*)  d_in[5];
    const float* dsc= (const float*)d_in[6];

    char* ws = (char*)d_ws;
    signed char*    Xq   = (signed char*)ws;    ws += (size_t)NTOK * D_MODEL;
    float*          xs   = (float*)ws;          ws += (size_t)NTOK * 4;
    signed char*    Wgu8 = (signed char*)ws;    ws += (size_t)2 * D_FF * D_MODEL;
    unsigned short* Wd   = (unsigned short*)ws; ws += (size_t)D_MODEL * D_FF * 2;
    unsigned short* H    = (unsigned short*)ws;

    const long long wtot  = (long long)D_FF * D_MODEL;
    const long long gutot = 2LL * wtot;

    hipFuncSetAttribute(reinterpret_cast<const void*>(gemm_i8gu),
                        hipFuncAttributeMaxDynamicSharedMemorySize, 65536);
    hipFuncSetAttribute(reinterpret_cast<const void*>(gemm256_down),
                        hipFuncAttributeMaxDynamicSharedMemorySize, 65536);

    pack_gu_kernel  <<<(int)(gutot / 2048), 256, 0, stream>>>(gw, uw, Wgu8);
    dequant_w_kernel<<<(int)(wtot  / 2048), 256, 0, stream>>>(dw, dsc, Wd, D_FF, wtot);
    quant_x_kernel  <<<NTOK, 256, 0, stream>>>(x, Xq, xs);

    // fused gate+up: H = silu(Xq@Wg^T * gs*xs) * (Xq@Wu^T * us*xs)
    dim3 g1(2 * D_FF / 256, NTOK / 256);   // 86 x 32 = 2752 blocks (%8==0)
    gemm_i8gu<<<g1, 512, 65536, stream>>>(Xq, Wgu8, H, xs, gs, us,
                                          NTOK, D_FF, D_MODEL);

    // out = H @ Wd^T -> f32
    dim3 g3(D_MODEL / 256, NTOK / 256);    // 16 x 32 = 512 blocks (%8==0)
    gemm256_down<<<g3, 512, 65536, stream>>>(H, Wd, (float*)d_out,
                                             NTOK, D_MODEL, D_FF);
}

// Round 10
// 1554.864 us; speedup vs baseline: 1.5633x; 1.5633x over previous
//
#include <hip/hip_runtime.h>

// ---------------------------------------------------------------------------
// SharedOnlyMLP r10: r7 structure with minimal barriers (1 per K-step).
//   Both GEMMs: 4-ring LDS (stage s+2 during s), ONE {vmcnt(4); s_barrier}
//   per step; 12 ds_reads + 32 MFMA per barrier region -> waves desync
//   within the step and LDS reads overlap MFMA across waves.
//   i8gu: BK=64, mfma_i32_16x16x64_i8, interleaved gate/up (r7 epilogue).
//   down: BK=32, mfma_f32_16x16x32_bf16, same ring geometry (T=344).
//   Occupancy is register-bound (2 waves/SIMD) -- LDS 128KB is free.
// ---------------------------------------------------------------------------

typedef __attribute__((ext_vector_type(8))) __bf16 bf16x8;
typedef __attribute__((ext_vector_type(4))) float f32x4;
typedef __attribute__((ext_vector_type(8))) unsigned short ushort8;
typedef __attribute__((ext_vector_type(4))) int i32x4;

#define D_MODEL 4096
#define D_FF    11008
#define NTOK    8192

static __device__ __forceinline__ unsigned short f32_to_bf16(float f) {
    union { float f; unsigned u; } v; v.f = f;
    unsigned r = v.u + 0x7fffu + ((v.u >> 16) & 1u);
    return (unsigned short)(r >> 16);
}
static __device__ __forceinline__ void gload_lds16(const void* g, void* l) {
    __builtin_amdgcn_global_load_lds(
        (const __attribute__((address_space(1))) void*)g,
        (__attribute__((address_space(3))) void*)l, 16, 0, 0);
}

// ---- pack gate+up int32 -> interleaved int8 (16-row groups) ----
__global__ __launch_bounds__(256)
void pack_gu_kernel(const int* __restrict__ gw, const int* __restrict__ uw,
                    signed char* __restrict__ out)
{
    long long i = ((long long)blockIdx.x * 256 + threadIdx.x) * 8;
    const int r = (int)(i >> 12);
    const int k = (int)(i & 4095);
    const int src_row = ((r >> 5) << 4) + (r & 15);
    const int* src = ((r >> 4) & 1) ? uw : gw;
    const int* p = src + (size_t)src_row * D_MODEL + k;
    int4 w0 = *(const int4*)(p);
    int4 w1 = *(const int4*)(p + 4);
    union { signed char c[8]; unsigned long long u; } rr;
    rr.c[0] = (signed char)w0.x; rr.c[1] = (signed char)w0.y;
    rr.c[2] = (signed char)w0.z; rr.c[3] = (signed char)w0.w;
    rr.c[4] = (signed char)w1.x; rr.c[5] = (signed char)w1.y;
    rr.c[6] = (signed char)w1.z; rr.c[7] = (signed char)w1.w;
    *(unsigned long long*)(out + i) = rr.u;
}

// ---- weight dequant (down-proj): int32 * s[row] -> bf16 ----
__global__ __launch_bounds__(256)
void dequant_w_kernel(const int* __restrict__ w, const float* __restrict__ s,
                      unsigned short* __restrict__ out, int cols, long long total)
{
    long long i = ((long long)blockIdx.x * 256 + threadIdx.x) * 8;
    if (i >= total) return;
    float sc = s[(int)(i / cols)];
    int4 w0 = *(const int4*)(w + i);
    int4 w1 = *(const int4*)(w + i + 4);
    ushort8 r;
    r[0] = f32_to_bf16((float)w0.x * sc);
    r[1] = f32_to_bf16((float)w0.y * sc);
    r[2] = f32_to_bf16((float)w0.z * sc);
    r[3] = f32_to_bf16((float)w0.w * sc);
    r[4] = f32_to_bf16((float)w1.x * sc);
    r[5] = f32_to_bf16((float)w1.y * sc);
    r[6] = f32_to_bf16((float)w1.z * sc);
    r[7] = f32_to_bf16((float)w1.w * sc);
    *(ushort8*)(out + i) = r;
}

// ---- x: f32 -> per-row int8 + scale ----
__global__ __launch_bounds__(256)
void quant_x_kernel(const float* __restrict__ x, signed char* __restrict__ xq,
                    float* __restrict__ xs)
{
    __shared__ float red[4];
    const int row = blockIdx.x;
    const int t   = threadIdx.x;
    const float* xr = x + (size_t)row * D_MODEL;
    float4 v0 = *(const float4*)(xr + t * 16);
    float4 v1 = *(const float4*)(xr + t * 16 + 4);
    float4 v2 = *(const float4*)(xr + t * 16 + 8);
    float4 v3 = *(const float4*)(xr + t * 16 + 12);
    float m = fabsf(v0.x);
    m = fmaxf(m, fabsf(v0.y)); m = fmaxf(m, fabsf(v0.z)); m = fmaxf(m, fabsf(v0.w));
    m = fmaxf(m, fabsf(v1.x)); m = fmaxf(m, fabsf(v1.y)); m = fmaxf(m, fabsf(v1.z)); m = fmaxf(m, fabsf(v1.w));
    m = fmaxf(m, fabsf(v2.x)); m = fmaxf(m, fabsf(v2.y)); m = fmaxf(m, fabsf(v2.z)); m = fmaxf(m, fabsf(v2.w));
    m = fmaxf(m, fabsf(v3.x)); m = fmaxf(m, fabsf(v3.y)); m = fmaxf(m, fabsf(v3.z)); m = fmaxf(m, fabsf(v3.w));
    #pragma unroll
    for (int o = 32; o > 0; o >>= 1) m = fmaxf(m, __shfl_xor(m, o));
    if ((t & 63) == 0) red[t >> 6] = m;
    __syncthreads();
    m = fmaxf(fmaxf(red[0], red[1]), fmaxf(red[2], red[3]));
    m = fmaxf(m, 1e-20f);
    const float inv = 127.0f / m;
    if (t == 0) xs[row] = m / 127.0f;
    union { signed char c[16]; int4 i; } r;
    #pragma unroll
    for (int j = 0; j < 4; ++j) {
        float4 v = (j == 0) ? v0 : (j == 1) ? v1 : (j == 2) ? v2 : v3;
        r.c[j*4+0] = (signed char)(int)rintf(fminf(fmaxf(v.x*inv,-127.f),127.f));
        r.c[j*4+1] = (signed char)(int)rintf(fminf(fmaxf(v.y*inv,-127.f),127.f));
        r.c[j*4+2] = (signed char)(int)rintf(fminf(fmaxf(v.z*inv,-127.f),127.f));
        r.c[j*4+3] = (signed char)(int)rintf(fminf(fmaxf(v.w*inv,-127.f),127.f));
    }
    *(int4*)(xq + (size_t)row * D_MODEL + t * 16) = r.i;
}

// ---------------------------------------------------------------------------
// Fused gate+up i8 GEMM. BK=64 steps, 4-ring of 32KB {A 16K, B 16K}.
// One barrier region per step: stage(s+2) + 12 ds_reads + 32 MFMA,
// then {vmcnt(4); s_barrier}.
// ---------------------------------------------------------------------------
__global__ __launch_bounds__(512, 2)
void gemm_i8gu(const signed char* __restrict__ A,
               const signed char* __restrict__ B,   // interleaved [2*D_FF][K]
               unsigned short* __restrict__ H,
               const float* __restrict__ xs,
               const float* __restrict__ gs,
               const float* __restrict__ us,
               int M, int NH, int K)
{
    extern __shared__ char smem[];
    const int tid = threadIdx.x;
    const int l   = tid & 63;
    const int w   = tid >> 6;
    const int wm  = w >> 2;
    const int wn  = w & 3;

    const int nbx  = gridDim.x;
    const int nwg  = nbx * gridDim.y;
    const int orig = blockIdx.y * nbx + blockIdx.x;
    const int cpx  = nwg >> 3;
    const int swz  = (orig & 7) * cpx + (orig >> 3);
    const int bn = swz % nbx, bm = swz / nbx;
    const int m0 = bm * 256, n0 = bn * 256;

    const int st_r = tid >> 2;
    const int st_c = ((tid & 3) ^ ((st_r >> 1) & 3)) << 4;
    const signed char* gA = A + (size_t)(m0 + st_r) * K + st_c;
    const signed char* gB = B + (size_t)(n0 + st_r) * K + st_c;
    const size_t ld128 = (size_t)128 * K;

    const int s4v = l >> 4;
    const int rA = wm * 128 + (l & 15);
    const int rB = wn * 64  + (l & 15);
    const int offA = rA * 64 + ((s4v << 4) ^ (((rA >> 1) & 3) << 4));
    const int offB = 16384 + rB * 64 + ((s4v << 4) ^ (((rB >> 1) & 3) << 4));

    i32x4 acc[8][4] = {};
    i32x4 af[8], bfr[4];

#define SBAR()  __builtin_amdgcn_sched_barrier(0)
#define BAR()   __builtin_amdgcn_s_barrier()
#define VM4()   asm volatile("s_waitcnt vmcnt(4)" ::: "memory")

#define ST_A8(SS, NXT) do { \
    const signed char* p_ = gA + ((size_t)(SS) << 6); \
    gload_lds16(p_,         smem + (NXT) + (w << 10)); \
    gload_lds16(p_ + ld128, smem + (NXT) + 8192 + (w << 10)); } while (0)
#define ST_B8(SS, NXT) do { \
    const signed char* p_ = gB + ((size_t)(SS) << 6); \
    gload_lds16(p_,         smem + (NXT) + 16384 + (w << 10)); \
    gload_lds16(p_ + 16384 - 8192 + 0, smem, 0); } while (0)
#undef ST_B8
#define ST_B8(SS, NXT) do { \
    const signed char* p_ = gB + ((size_t)(SS) << 6); \
    gload_lds16(p_,         smem + (NXT) + 16384 + (w << 10)); \
    gload_lds16(p_ + ld128, smem + (NXT) + 16384 + 8192 + (w << 10)); } while (0)

// one barrier region per BK=64 step
#define STEP8(CUR, NXT, SS) do { \
    ST_A8(SS, NXT); \
    ST_B8(SS, NXT); \
    af[0] = *(const i32x4*)(smem + (CUR) + offA); \
    af[1] = *(const i32x4*)(smem + (CUR) + offA + 1024); \
    af[2] = *(const i32x4*)(smem + (CUR) + offA + 2048); \
    af[3] = *(const i32x4*)(smem + (CUR) + offA + 3072); \
    af[4] = *(const i32x4*)(smem + (CUR) + offA + 4096); \
    af[5] = *(const i32x4*)(smem + (CUR) + offA + 5120); \
    af[6] = *(const i32x4*)(smem + (CUR) + offA + 6144); \
    af[7] = *(const i32x4*)(smem + (CUR) + offA + 7168); \
    bfr[0] = *(const i32x4*)(smem + (CUR) + offB); \
    bfr[1] = *(const i32x4*)(smem + (CUR) + offB + 1024); \
    bfr[2] = *(const i32x4*)(smem + (CUR) + offB + 2048); \
    bfr[3] = *(const i32x4*)(smem + (CUR) + offB + 3072); \
    __builtin_amdgcn_s_setprio(1); \
    _Pragma("unroll") \
    for (int mi_ = 0; mi_ < 8; ++mi_) { \
        _Pragma("unroll") \
        for (int ni_ = 0; ni_ < 4; ++ni_) { \
            acc[mi_][ni_] = __builtin_amdgcn_mfma_i32_16x16x64_i8( \
                af[mi_], bfr[ni_], acc[mi_][ni_], 0, 0, 0); \
        } } \
    __builtin_amdgcn_s_setprio(0); \
    VM4(); SBAR(); BAR(); \
} while (0)

    // prologue: stage steps 0,1 into bufs 0,1; wait step 0 (oldest 4)
    ST_A8(0, 0);      ST_B8(0, 0);
    ST_A8(1, 32768);  ST_B8(1, 32768);
    VM4(); SBAR(); BAR();

    const int T = K >> 6;            // 64; T%4==0
    #pragma unroll 1
    for (int s = 0; s < T; s += 4) {
        int s2 = s + 2; if (s2 >= T) s2 -= T;
        int s3 = s + 3; if (s3 >= T) s3 -= T;
        int s4 = s + 4; if (s4 >= T) s4 -= T;
        int s5 = s + 5; if (s5 >= T) s5 -= T;
        STEP8(0,     65536, s2);
        STEP8(32768, 98304, s3);
        STEP8(65536, 0,     s4);
        STEP8(98304, 32768, s5);
    }
    asm volatile("s_waitcnt vmcnt(0)" ::: "memory");

    // epilogue: ni even = gate, ni odd = up (16-row interleave, r7-proven)
    const int er = (l >> 4) * 4;
    const int ec = l & 15;
    const int hbase = (n0 >> 1) + wn * 32;
    #pragma unroll
    for (int mi = 0; mi < 8; ++mi) {
        const int rowb = m0 + wm * 128 + mi * 16 + er;
        const float4 xsv = *(const float4*)(xs + rowb);
        #pragma unroll
        for (int p = 0; p < 2; ++p) {
            const int c = hbase + p * 16 + ec;
            const float sg = gs[c];
            const float su = us[c];
            #pragma unroll
            for (int q = 0; q < 4; ++q) {
                const float xsc = (q == 0) ? xsv.x : (q == 1) ? xsv.y
                                 : (q == 2) ? xsv.z : xsv.w;
                float g = (float)acc[mi][2*p][q]     * sg * xsc;
                float u = (float)acc[mi][2*p + 1][q] * su * xsc;
                float sig = 1.0f / (1.0f + __expf(-g));
                H[(size_t)(rowb + q) * NH + c] = f32_to_bf16(g * sig * u);
            }
        }
    }
#undef STEP8
#undef ST_A8
#undef ST_B8
#undef VM4
#undef BAR
#undef SBAR
}

// ---------------------------------------------------------------------------
// Down-proj bf16 GEMM. BK=32 steps, 4-ring of 32KB {A 16K, B 16K} --
// byte-identical ring geometry to i8gu. One barrier region per step
// (12 ds_reads + 32 MFMA), {vmcnt(4); s_barrier}. T = 344.
// ---------------------------------------------------------------------------
__global__ __launch_bounds__(512, 2)
void gemm256_down(const unsigned short* __restrict__ A,
                  const unsigned short* __restrict__ B,
                  float* __restrict__ C,
                  int M, int N, int K)
{
    extern __shared__ char smem[];
    const int tid = threadIdx.x;
    const int l   = tid & 63;
    const int w   = tid >> 6;
    const int wm  = w >> 2;
    const int wn  = w & 3;

    const int nbx  = gridDim.x;
    const int nwg  = nbx * gridDim.y;
    const int orig = blockIdx.y * nbx + blockIdx.x;
    const int cpx  = nwg >> 3;
    const int swz  = (orig & 7) * cpx + (orig >> 3);
    const int bn = swz % nbx, bm = swz / nbx;
    const int m0 = bm * 256, n0 = bn * 256;

    // staging: thread t -> row t>>2 (+128), 16B chunk (t&3), pre-swizzled src
    const int st_r = tid >> 2;
    const int st_c = ((tid & 3) ^ ((st_r >> 1) & 3)) << 3;   // elems (bf16)
    const unsigned short* gA = A + (size_t)(m0 + st_r) * K + st_c;
    const unsigned short* gB = B + (size_t)(n0 + st_r) * K + st_c;
    const size_t ld128 = (size_t)128 * K;

    const int s4v = l >> 4;
    const int rA = wm * 128 + (l & 15);
    const int rB = wn * 64  + (l & 15);
    const int offA = rA * 64 + ((s4v << 4) ^ (((rA >> 1) & 3) << 4));
    const int offB = 16384 + rB * 64 + ((s4v << 4) ^ (((rB >> 1) & 3) << 4));

    f32x4 acc[8][4] = {};
    bf16x8 af[8], bfr[4];

#define SBAR()  __builtin_amdgcn_sched_barrier(0)
#define BAR()   __builtin_amdgcn_s_barrier()
#define VM4()   asm volatile("s_waitcnt vmcnt(4)" ::: "memory")

#define ST_A2(SS, NXT) do { \
    const unsigned short* p_ = gA + ((size_t)(SS) << 5); \
    gload_lds16(p_,         smem + (NXT) + (w << 10)); \
    gload_lds16(p_ + ld128, smem + (NXT) + 8192 + (w << 10)); } while (0)
#define ST_B2(SS, NXT) do { \
    const unsigned short* p_ = gB + ((size_t)(SS) << 5); \
    gload_lds16(p_,         smem + (NXT) + 16384 + (w << 10)); \
    gload_lds16(p_ + ld128, smem + (NXT) + 16384 + 8192 + (w << 10)); } while (0)

// one barrier region per BK=32 step
#define STEPD(CUR, NXT, SS) do { \
    ST_A2(SS, NXT); \
    ST_B2(SS, NXT); \
    af[0] = *(const bf16x8*)(smem + (CUR) + offA); \
    af[1] = *(const bf16x8*)(smem + (CUR) + offA + 1024); \
    af[2] = *(const bf16x8*)(smem + (CUR) + offA + 2048); \
    af[3] = *(const bf16x8*)(smem + (CUR) + offA + 3072); \
    af[4] = *(const bf16x8*)(smem + (CUR) + offA + 4096); \
    af[5] = *(const bf16x8*)(smem + (CUR) + offA + 5120); \
    af[6] = *(const bf16x8*)(smem + (CUR) + offA + 6144); \
    af[7] = *(const bf16x8*)(smem + (CUR) + offA + 7168); \
    bfr[0] = *(const bf16x8*)(smem + (CUR) + offB); \
    bfr[1] = *(const bf16x8*)(smem + (CUR) + offB + 1024); \
    bfr[2] = *(const bf16x8*)(smem + (CUR) + offB + 2048); \
    bfr[3] = *(const bf16x8*)(smem + (CUR) + offB + 3072); \
    __builtin_amdgcn_s_setprio(1); \
    _Pragma("unroll") \
    for (int mi_ = 0; mi_ < 8; ++mi_) { \
        _Pragma("unroll") \
        for (int ni_ = 0; ni_ < 4; ++ni_) { \
            acc[mi_][ni_] = __builtin_amdgcn_mfma_f32_16x16x32_bf16( \
                af[mi_], bfr[ni_], acc[mi_][ni_], 0, 0, 0); \
        } } \
    __builtin_amdgcn_s_setprio(0); \
    VM4(); SBAR(); BAR(); \
} while (0)

    // prologue: stage steps 0,1; wait step 0
    ST_A2(0, 0);      ST_B2(0, 0);
    ST_A2(1, 32768);  ST_B2(1, 32768);
    VM4(); SBAR(); BAR();

    const int T = K >> 5;            // 344; T%4==0
    #pragma unroll 1
    for (int s = 0; s < T; s += 4) {
        int s2 = s + 2; if (s2 >= T) s2 -= T;
        int s3 = s + 3; if (s3 >= T) s3 -= T;
        int s4 = s + 4; if (s4 >= T) s4 -= T;
        int s5 = s + 5; if (s5 >= T) s5 -= T;
        STEPD(0,     65536, s2);
        STEPD(32768, 98304, s3);
        STEPD(65536, 0,     s4);
        STEPD(98304, 32768, s5);
    }
    asm volatile("s_waitcnt vmcnt(0)" ::: "memory");

    const int er = (l >> 4) * 4;
    const int ec = l & 15;
    #pragma unroll
    for (int mi = 0; mi < 8; ++mi) {
        #pragma unroll
        for (int ni = 0; ni < 4; ++ni) {
            #pragma unroll
            for (int q = 0; q < 4; ++q) {
                int row = m0 + wm * 128 + mi * 16 + er + q;
                int col = n0 + wn * 64  + ni * 16 + ec;
                C[(size_t)row * N + col] = acc[mi][ni][q];
            }
        }
    }
#undef STEPD
#undef ST_A2
#undef ST_B2
#undef VM4
#undef BAR
#undef SBAR
}

extern "C" void kernel_launch(void* const* d_in, const int* in_sizes, int n_in,
                              void* d_out, int out_size, void* d_ws, size_t ws_size,
                              hipStream_t stream)
{
    const float* x  = (const float*)d_in[0];
    const int*   gw = (const int*)  d_in[1];
    const float* gs = (const float*)d_in[2];
    const int*   uw = (const int*)  d_in[3];
    const float* us = (const float*)d_in[4];
    const int*   dw = (const int*)  d_in[5];
    const float* dsc= (const float*)d_in[6];

    char* ws = (char*)d_ws;
    signed char*    Xq   = (signed char*)ws;    ws += (size_t)NTOK * D_MODEL;
    float*          xs   = (float*)ws;          ws += (size_t)NTOK * 4;
    signed char*    Wgu8 = (signed char*)ws;    ws += (size_t)2 * D_FF * D_MODEL;
    unsigned short* Wd   = (unsigned short*)ws; ws += (size_t)D_MODEL * D_FF * 2;
    unsigned short* H    = (unsigned short*)ws;

    const long long wtot  = (long long)D_FF * D_MODEL;
    const long long gutot = 2LL * wtot;

    hipFuncSetAttribute(reinterpret_cast<const void*>(gemm_i8gu),
                        hipFuncAttributeMaxDynamicSharedMemorySize, 131072);
    hipFuncSetAttribute(reinterpret_cast<const void*>(gemm256_down),
                        hipFuncAttributeMaxDynamicSharedMemorySize, 131072);

    pack_gu_kernel  <<<(int)(gutot / 2048), 256, 0, stream>>>(gw, uw, Wgu8);
    dequant_w_kernel<<<(int)(wtot  / 2048), 256, 0, stream>>>(dw, dsc, Wd, D_FF, wtot);
    quant_x_kernel  <<<NTOK, 256, 0, stream>>>(x, Xq, xs);

    // fused gate+up: H = silu(Xq@Wg^T * gs*xs) * (Xq@Wu^T * us*xs)
    dim3 g1(2 * D_FF / 256, NTOK / 256);   // 86 x 32 = 2752 blocks (%8==0)
    gemm_i8gu<<<g1, 512, 131072, stream>>>(Xq, Wgu8, H, xs, gs, us,
                                           NTOK, D_FF, D_MODEL);

    // out = H @ Wd^T -> f32
    dim3 g3(D_MODEL / 256, NTOK / 256);    // 16 x 32 = 512 blocks (%8==0)
    gemm256_down<<<g3, 512, 131072, stream>>>(H, Wd, (float*)d_out,
                                              NTOK, D_MODEL, D_FF);
}